// Round 8
// baseline (363.668 us; speedup 1.0000x reference)
//
#include <hip/hip_runtime.h>

typedef short bf16x8 __attribute__((ext_vector_type(8)));
typedef float f32x4  __attribute__((ext_vector_type(4)));
typedef unsigned int u32;
typedef unsigned short u16;
typedef u32 u32x4 __attribute__((ext_vector_type(4)));

#define NBATCH 16
#define C      512
#define NPIX   4096
#define ATT_OFF ((size_t)NBATCH * 1024 * NPIX)   // 67,108,864 floats

// split one f32 pair (as raw bits) -> packed bf16 hi pair + bf16 lo pair
__device__ __forceinline__ void splitpair(u32 u0, u32 u1, u32& h, u32& l) {
    h = __builtin_amdgcn_perm(u1, u0, 0x07060302u);
    const u32 m0 = u0 & 0xFFFF0000u, m1 = u1 & 0xFFFF0000u;
    const float l0 = __uint_as_float(u0) - __uint_as_float(m0);
    const float l1 = __uint_as_float(u1) - __uint_as_float(m1);
    l = __builtin_amdgcn_perm(__float_as_uint(l1), __float_as_uint(l0), 0x07060302u);
}

// ---------------------------------------------------------------------------
// GEMM1: energy[b,i,j] = sum_n x1[b,i,n]*x2[b,j,n]  (split-bf16, 3 MFMA)
// LDS-FREE / barrier-free: both operands are k-contiguous (NT), so MFMA
// fragments load straight from global (L2) into registers as RAW BITS
// (u32x4 — bitcast, NOT float->int conversion; that was round 7's bug).
// 512 blocks (2/CU), split-K=2. jb,ib innermost per XCD for L2 reuse.
// ks=0 partial -> att slot; ks=1 partial -> park (front of av region).
// ---------------------------------------------------------------------------
__global__ __launch_bounds__(256, 2) void gemm1_energy(
    const float* __restrict__ x1, const float* __restrict__ x2,
    float* __restrict__ out)
{
    const int tid  = threadIdx.x;
    const int lane = tid & 63;
    const int w    = tid >> 6;
    const int wr   = (w >> 1) * 64;
    const int wc   = (w & 1) * 64;
    const int r16  = lane & 15;
    const int g    = lane >> 4;

    const int gid = (blockIdx.x & 7) * 64 + (blockIdx.x >> 3);  // XCD swizzle (512%8==0)
    const int jb  = (gid & 3) * 128;
    const int ib  = ((gid >> 2) & 3) * 128;
    const int b   = (gid >> 4) & 15;
    const int ks  = gid >> 8;
    const int ko  = ks * 2048;

    // per-fragment global base pointers (32B contiguous per lane)
    const float* Ap[4];
    const float* Bp[4];
    #pragma unroll
    for (int f = 0; f < 4; ++f) {
        Ap[f] = x1 + (size_t)(b * C + ib + wr + f * 16 + r16) * NPIX + ko + g * 8;
        Bp[f] = x2 + (size_t)(b * C + jb + wc + f * 16 + r16) * NPIX + ko + g * 8;
    }

    const f32x4 zero4 = {0.f, 0.f, 0.f, 0.f};
    f32x4 acc[4][4];
    #pragma unroll
    for (int i = 0; i < 4; ++i)
        #pragma unroll
        for (int j = 0; j < 4; ++j) acc[i][j] = zero4;

    union B8 { bf16x8 v; u32 u[4]; };

    u32x4 UA[4][2], UB[4][2];                   // RAW BITS of 8 f32 per frag
    #pragma unroll
    for (int f = 0; f < 4; ++f) {               // prologue: kt=0 loads
        UA[f][0] = *(const u32x4*)(Ap[f]);
        UA[f][1] = *(const u32x4*)(Ap[f] + 4);
        UB[f][0] = *(const u32x4*)(Bp[f]);
        UB[f][1] = *(const u32x4*)(Bp[f] + 4);
    }

    for (int kt = 0; kt < 64; ++kt) {
        // split current tile into bf16 hi/lo fragments (U becomes dead)
        B8 ah[4], al[4], bh[4], bl[4];
        #pragma unroll
        for (int f = 0; f < 4; ++f) {
            splitpair(UA[f][0].x, UA[f][0].y, ah[f].u[0], al[f].u[0]);
            splitpair(UA[f][0].z, UA[f][0].w, ah[f].u[1], al[f].u[1]);
            splitpair(UA[f][1].x, UA[f][1].y, ah[f].u[2], al[f].u[2]);
            splitpair(UA[f][1].z, UA[f][1].w, ah[f].u[3], al[f].u[3]);
            splitpair(UB[f][0].x, UB[f][0].y, bh[f].u[0], bl[f].u[0]);
            splitpair(UB[f][0].z, UB[f][0].w, bh[f].u[1], bl[f].u[1]);
            splitpair(UB[f][1].x, UB[f][1].y, bh[f].u[2], bl[f].u[2]);
            splitpair(UB[f][1].z, UB[f][1].w, bh[f].u[3], bl[f].u[3]);
        }

        // issue next tile's loads now; they fly during the 48 MFMAs
        if (kt < 63) {
            const int off = (kt + 1) * 32;
            #pragma unroll
            for (int f = 0; f < 4; ++f) {
                UA[f][0] = *(const u32x4*)(Ap[f] + off);
                UA[f][1] = *(const u32x4*)(Ap[f] + off + 4);
                UB[f][0] = *(const u32x4*)(Bp[f] + off);
                UB[f][1] = *(const u32x4*)(Bp[f] + off + 4);
            }
        }

        __builtin_amdgcn_s_setprio(1);
        #pragma unroll
        for (int fi = 0; fi < 4; ++fi)
            #pragma unroll
            for (int fj = 0; fj < 4; ++fj) {
                acc[fi][fj] = __builtin_amdgcn_mfma_f32_16x16x32_bf16(ah[fi].v, bh[fj].v, acc[fi][fj], 0, 0, 0);
                acc[fi][fj] = __builtin_amdgcn_mfma_f32_16x16x32_bf16(ah[fi].v, bl[fj].v, acc[fi][fj], 0, 0, 0);
                acc[fi][fj] = __builtin_amdgcn_mfma_f32_16x16x32_bf16(al[fi].v, bh[fj].v, acc[fi][fj], 0, 0, 0);
            }
        __builtin_amdgcn_s_setprio(0);
    }

    // partial energies: ks=0 -> att slot; ks=1 -> park (front of av region)
    float* dst = (ks == 0) ? (out + ATT_OFF + (size_t)b * C * C)
                           : (out + (size_t)(b * 1024 + 512) * NPIX);
    #pragma unroll
    for (int fi = 0; fi < 4; ++fi)
        #pragma unroll
        for (int fj = 0; fj < 4; ++fj) {
            const int j = jb + wc + fj * 16 + r16;
            #pragma unroll
            for (int q = 0; q < 4; ++q) {
                const int i = ib + wr + fi * 16 + g * 4 + q;
                dst[(size_t)i * C + j] = acc[fi][fj][q];
            }
        }
}

// ---------------------------------------------------------------------------
// Softmax over last dim (512): adds the two split-K partials, softmaxes,
// writes final attention into the att slot.
// ---------------------------------------------------------------------------
__global__ __launch_bounds__(256) void softmax_rows(float* __restrict__ out)
{
    const int bi = blockIdx.x;          // b*512 + i
    const int b  = bi >> 9;
    const int i  = bi & 511;
    float* p        = out + ATT_OFF + (size_t)bi * C;
    const float* pk = out + (size_t)(b * 1024 + 512) * NPIX + (size_t)i * C;

    const int t = threadIdx.x;
    const int lane = t & 63, wid = t >> 6;
    __shared__ float red[8];

    float a = p[t] + pk[t];
    float c = p[t + 256] + pk[t + 256];
    float m = fmaxf(a, c);
    #pragma unroll
    for (int o = 32; o; o >>= 1) m = fmaxf(m, __shfl_xor(m, o));
    if (lane == 0) red[wid] = m;
    __syncthreads();
    m = fmaxf(fmaxf(red[0], red[1]), fmaxf(red[2], red[3]));

    float e0 = __expf(a - m), e1 = __expf(c - m);
    float s = e0 + e1;
    #pragma unroll
    for (int o = 32; o; o >>= 1) s += __shfl_xor(s, o);
    if (lane == 0) red[4 + wid] = s;
    __syncthreads();
    s = (red[4] + red[5]) + (red[6] + red[7]);
    const float inv = 1.0f / s;
    p[t]       = e0 * inv;
    p[t + 256] = e1 * inv;
}

// ---------------------------------------------------------------------------
// GEMM2: av[b,j,n] = sum_k att[b,k,j] * x1[b,k,n]   (TT, K=512, bf16 MFMA)
// Deferred pack (T14). jt fastest in gid so the 4 blocks sharing an x1
// n-panel are dispatch-adjacent on the same XCD -> L2 absorbs re-reads.
// jt==0 blocks also copy their staged x1 f32 tile to out channels [0,512).
// ---------------------------------------------------------------------------
#define KST 36   // u16 stride per LDS row (32 + 4 pad)

__global__ __launch_bounds__(256, 3) void gemm2_av(
    const float* __restrict__ x1, float* __restrict__ out)
{
    __shared__ __align__(16) u16 Aj[2][128 * KST];  // att^T tile: row j, k 0..31
    __shared__ __align__(16) u16 Bn[2][128 * KST];  // x1^T tile: row n, k 0..31

    const float* att = out + ATT_OFF;
    const int tid  = threadIdx.x;
    const int lane = tid & 63;
    const int wid  = tid >> 6;
    const int wr   = (wid >> 1) * 64;   // j
    const int wc   = (wid & 1) * 64;    // n
    const int r16  = lane & 15;
    const int g    = lane >> 4;

    const int gid = (blockIdx.x & 7) * 256 + (blockIdx.x >> 3);  // XCD swizzle
    const int jt  = gid & 3;            // fastest: same-panel blocks adjacent
    const int nt  = (gid >> 2) & 31;
    const int b   = gid >> 7;
    const int jb  = jt * 128;
    const int nb  = nt * 128;

    const int col = (tid & 31) * 4;     // j (or n) column group staged
    const int ksr = (tid >> 5) * 4;     // 4 k's per thread per tile

    const float* ap0 = att + (size_t)b * C * C    + (size_t)ksr * C    + jb + col;
    const float* bp0 = x1  + (size_t)b * C * NPIX + (size_t)ksr * NPIX + nb + col;
    float* cpy = out + (size_t)(b * 1024 + ksr) * NPIX + nb + col;

    f32x4 La[4], Lb[4];

    auto loadk = [&](int kt) {
        #pragma unroll
        for (int i = 0; i < 4; ++i) {
            La[i] = *(const f32x4*)(ap0 + (size_t)(kt * 32 + i) * C);
            Lb[i] = *(const f32x4*)(bp0 + (size_t)(kt * 32 + i) * NPIX);
        }
    };

    auto stage = [&](int kt, int buf) {
        u32 sa[8], sb[8];
        #pragma unroll
        for (int jj = 0; jj < 4; ++jj) {
            sa[jj * 2]     = __builtin_amdgcn_perm(__float_as_uint(La[1][jj]), __float_as_uint(La[0][jj]), 0x07060302u);
            sa[jj * 2 + 1] = __builtin_amdgcn_perm(__float_as_uint(La[3][jj]), __float_as_uint(La[2][jj]), 0x07060302u);
            sb[jj * 2]     = __builtin_amdgcn_perm(__float_as_uint(Lb[1][jj]), __float_as_uint(Lb[0][jj]), 0x07060302u);
            sb[jj * 2 + 1] = __builtin_amdgcn_perm(__float_as_uint(Lb[3][jj]), __float_as_uint(Lb[2][jj]), 0x07060302u);
        }
        #pragma unroll
        for (int jj = 0; jj < 4; ++jj) {
            *(uint2*)((char*)Aj[buf] + ((col + jj) * KST + ksr) * 2) = make_uint2(sa[jj * 2], sa[jj * 2 + 1]);
            *(uint2*)((char*)Bn[buf] + ((col + jj) * KST + ksr) * 2) = make_uint2(sb[jj * 2], sb[jj * 2 + 1]);
        }
        if (jt == 0) {                  // fused x1 -> out copy
            #pragma unroll
            for (int i = 0; i < 4; ++i)
                *(f32x4*)(cpy + (size_t)(kt * 32 + i) * NPIX) = Lb[i];
        }
    };

    const f32x4 zero4 = {0.f, 0.f, 0.f, 0.f};
    f32x4 acc[4][4];
    #pragma unroll
    for (int i = 0; i < 4; ++i)
        #pragma unroll
        for (int j = 0; j < 4; ++j) acc[i][j] = zero4;

    loadk(0);
    stage(0, 0);

    for (int kt = 0; kt < 16; ++kt) {
        if (kt < 15) loadk(kt + 1);     // raw loads issued early (T14)
        __syncthreads();
        const int buf = kt & 1;

        union { bf16x8 v; uint2 u2[2]; } fa[4], fb[4];
        #pragma unroll
        for (int f = 0; f < 4; ++f) {
            const int aj = wr + f * 16 + r16;
            fa[f].u2[0] = *(const uint2*)(&Aj[buf][aj * KST + g * 8]);
            fa[f].u2[1] = *(const uint2*)(&Aj[buf][aj * KST + g * 8 + 4]);
            const int bn = wc + f * 16 + r16;
            fb[f].u2[0] = *(const uint2*)(&Bn[buf][bn * KST + g * 8]);
            fb[f].u2[1] = *(const uint2*)(&Bn[buf][bn * KST + g * 8 + 4]);
        }
        __builtin_amdgcn_s_setprio(1);
        #pragma unroll
        for (int fi = 0; fi < 4; ++fi)
            #pragma unroll
            for (int fj = 0; fj < 4; ++fj)
                acc[fi][fj] = __builtin_amdgcn_mfma_f32_16x16x32_bf16(fa[fi].v, fb[fj].v, acc[fi][fj], 0, 0, 0);
        __builtin_amdgcn_s_setprio(0);
        if (kt < 15) stage(kt + 1, buf ^ 1);   // pack+write late (post-MFMA)
    }

    #pragma unroll
    for (int fi = 0; fi < 4; ++fi)
        #pragma unroll
        for (int fj = 0; fj < 4; ++fj) {
            const int n = nb + wc + fj * 16 + r16;
            #pragma unroll
            for (int q = 0; q < 4; ++q) {
                const int j = jb + wr + fi * 16 + g * 4 + q;
                out[(size_t)(b * 1024 + 512 + j) * NPIX + n] = acc[fi][fj][q];
            }
        }
}

extern "C" void kernel_launch(void* const* d_in, const int* in_sizes, int n_in,
                              void* d_out, int out_size, void* d_ws, size_t ws_size,
                              hipStream_t stream) {
    const float* x1 = (const float*)d_in[0];
    const float* x2 = (const float*)d_in[1];
    float* out = (float*)d_out;
    (void)in_sizes; (void)n_in; (void)out_size; (void)d_ws; (void)ws_size;

    gemm1_energy<<<dim3(512),  dim3(256), 0, stream>>>(x1, x2, out);
    softmax_rows<<<dim3(8192), dim3(256), 0, stream>>>(out);
    gemm2_av    <<<dim3(2048), dim3(256), 0, stream>>>(x1, out);
}